// Round 19
// baseline (233.472 us; speedup 1.0000x reference)
//
#include <hip/hip_runtime.h>

typedef float f32x4 __attribute__((ext_vector_type(4)));
typedef short short8v __attribute__((ext_vector_type(8)));

#define B_    2048
#define IDX_  32
#define NDIM_ 128
#define SDIM_ 64
#define EDGES 262144
#define NNODE 65536   // B_*32

__device__ __forceinline__ float fastrcp(float x) { return __builtin_amdgcn_rcpf(x); }
__device__ __forceinline__ float sigf(float x) { return fastrcp(1.0f + __expf(-x)); }
__device__ __forceinline__ float tanhfast(float x) {
  return 1.0f - 2.0f * fastrcp(1.0f + __expf(2.0f * x));
}

__device__ __forceinline__ unsigned short f2bf(float f) {        // RNE
  unsigned int u = __float_as_uint(f);
  return (unsigned short)((u + 0x7FFFu + ((u >> 16) & 1u)) >> 16);
}
__device__ __forceinline__ float bf2f(unsigned int h) {
  return __uint_as_float(h << 16);
}
__device__ __forceinline__ unsigned int pack2(float a, float b) {
  return (unsigned int)f2bf(a) | ((unsigned int)f2bf(b) << 16);
}

// ---------------------------------------------------------------------------
// one-time conversions. All weight buffers are packed into MFMA-FRAGMENT
// order [ctile][kb][lane][8]: lane l supplies B-row (ct*16 + (l&15)) elems
// k = kb*32 + (l>>4)*8 .. +8. A wave's fragment load is then one coalesced
// 1KB burst instead of a 16-line gather.
// ---------------------------------------------------------------------------
__global__ __launch_bounds__(256) void convert_all_kernel(
    const float* __restrict__ h,    const float* __restrict__ msgW,
    const float* __restrict__ Wih,  const float* __restrict__ Whh,
    const float* __restrict__ fmW,  const float* __restrict__ fmiW,
    unsigned short* __restrict__ hb,
    unsigned short* __restrict__ wm, unsigned short* __restrict__ wrz,
    unsigned short* __restrict__ wni, unsigned short* __restrict__ wnh,
    unsigned short* __restrict__ wcat, int* __restrict__ cnt)
{
  int id = blockIdx.x * 256 + threadIdx.x;       // [0, 1048576)
  if (id < 2 * 256 * 256) {                      // wrzP: 256 ch x 256 k, 2 layers
    int l = id >> 16, pid = id & 65535;
    int e = pid & 7, lane = (pid >> 3) & 63, kb = (pid >> 9) & 7, ct = pid >> 12;
    int c = ct * 16 + (lane & 15);
    int k = kb * 32 + (lane >> 4) * 8 + e;
    const float* base = (k < 128) ? Wih : Whh;
    wrz[id] = f2bf(base[(size_t)l * 384 * 128 + (size_t)c * 128 + (k & 127)]);
  }
  if (id < 2 * 256 * 128) {                      // wmP: 256 vch x 128 k, 2 layers
    int l = id >> 15, pid = id & 32767;
    int e = pid & 7, lane = (pid >> 3) & 63, kb = (pid >> 9) & 3, ct = pid >> 11;
    int u = ct * 16 + (lane & 15);
    int k = kb * 32 + (lane >> 4) * 8 + e;
    wm[id] = f2bf(msgW[(size_t)l * 128 * 256 + (size_t)(u & 127) * 256
                       + ((u >> 7) << 7) + k]);
  }
  if (id < 2 * 128 * 128) {                      // wniP / wnhP: 128 ch x 128 k
    int l = id >> 14, pid = id & 16383;
    int e = pid & 7, lane = (pid >> 3) & 63, kb = (pid >> 9) & 3, ct = pid >> 11;
    int c = ct * 16 + (lane & 15);
    int k = kb * 32 + (lane >> 4) * 8 + e;
    size_t src = (size_t)l * 384 * 128 + (size_t)(256 + c) * 128 + k;
    wni[id] = f2bf(Wih[src]);
    wnh[id] = f2bf(Whh[src]);
  }
  if (id < 128 * 128) {                          // wcatP: 128 ch x 128 k
    int pid = id;
    int e = pid & 7, lane = (pid >> 3) & 63, kb = (pid >> 9) & 3, ct = pid >> 11;
    int c = ct * 16 + (lane & 15);
    int k = kb * 32 + (lane >> 4) * 8 + e;
    wcat[id] = f2bf(c < 64 ? fmW[(size_t)c * 128 + k]
                           : fmiW[(size_t)(c - 64) * 128 + k]);
  }
  if (id < NNODE) cnt[id] = 0;
  {
    size_t i = (size_t)id * 8;
    float4 a = *(const float4*)(h + i);
    float4 b = *(const float4*)(h + i + 4);
    uint4 o;
    o.x = pack2(a.x, a.y); o.y = pack2(a.z, a.w);
    o.z = pack2(b.x, b.y); o.w = pack2(b.z, b.w);
    *(uint4*)(hb + i) = o;
  }
}

// ---------------------------------------------------------------------------
// CSR build: hist -> 3-phase scan -> scatter
// ---------------------------------------------------------------------------
__global__ __launch_bounds__(256) void hist_kernel(
    const int* __restrict__ e0, const int* __restrict__ e1, int* __restrict__ cnt)
{
  int e = blockIdx.x * 256 + threadIdx.x;
  if (e < EDGES) {
    atomicAdd(&cnt[e1[e]], 1);
    atomicAdd(&cnt[e0[e]], 1);
  }
}

__global__ __launch_bounds__(256) void scan1_kernel(
    const int* __restrict__ cnt, int* __restrict__ offs, int* __restrict__ bsum)
{
  __shared__ int sh[256];
  const int t = threadIdx.x;
  const int i = blockIdx.x * 256 + t;
  int v = cnt[i];
  int x = v;
  sh[t] = x;
  __syncthreads();
#pragma unroll
  for (int off = 1; off < 256; off <<= 1) {
    int y = (t >= off) ? sh[t - off] : 0;
    __syncthreads();
    x += y; sh[t] = x;
    __syncthreads();
  }
  offs[i] = x - v;
  if (t == 255) bsum[blockIdx.x] = x;
}

__global__ __launch_bounds__(256) void scan2_kernel(int* __restrict__ bsum,
                                                    int* __restrict__ boff)
{
  __shared__ int sh[256];
  const int t = threadIdx.x;
  int v = bsum[t];
  int x = v;
  sh[t] = x;
  __syncthreads();
#pragma unroll
  for (int off = 1; off < 256; off <<= 1) {
    int y = (t >= off) ? sh[t - off] : 0;
    __syncthreads();
    x += y; sh[t] = x;
    __syncthreads();
  }
  boff[t] = x - v;
}

__global__ __launch_bounds__(256) void scan3_kernel(
    const int* __restrict__ cnt, int* __restrict__ offs,
    const int* __restrict__ boff, int* __restrict__ cur)
{
  const int i = blockIdx.x * 256 + threadIdx.x;
  int o = offs[i] + boff[blockIdx.x];
  offs[i] = o; cur[i] = o;
  if (i == NNODE - 1) offs[NNODE] = o + cnt[i];
}

__global__ __launch_bounds__(256) void scatter_kernel(
    const int* __restrict__ e0, const int* __restrict__ e1,
    int* __restrict__ cur, int* __restrict__ adj)
{
  int e = blockIdx.x * 256 + threadIdx.x;
  if (e < EDGES) {
    int a = e0[e], b = e1[e];
    int p = atomicAdd(&cur[b], 1); adj[p] = a;
    int q = atomicAdd(&cur[a], 1); adj[q] = b;
  }
}

// ---------------------------------------------------------------------------
// proj (MFMA, 64-node tiles, single LDS buffer, packed weights):
// P1 = hn@W1.T + msgb, P2 = hn@W2.T.
// ---------------------------------------------------------------------------
__global__ __launch_bounds__(256, 3) void proj_mfma_kernel(
    const unsigned short* __restrict__ hb, const unsigned short* __restrict__ Wbf,
    const float* __restrict__ msgb,
    unsigned short* __restrict__ P1, unsigned short* __restrict__ P2)
{
  __shared__ unsigned short xl[64 * 264];
  const int t = threadIdx.x, lane = t & 63, wv = t >> 6;
  const int n0 = blockIdx.x * 64;

#pragma unroll
  for (int i = 0; i < 4; ++i) {
    int id = t + 256 * i;
    int row = id >> 4, ch = id & 15;
    *(uint4*)(xl + row * 264 + ch * 8) =
        *(const uint4*)(hb + (size_t)(n0 + row) * 128 + ch * 8);
  }
  __syncthreads();

  const int cb = wv * 64;
  const int rlo = lane & 15;
  const int kg  = lane >> 4;
  f32x4 acc[4][4];
#pragma unroll
  for (int mt = 0; mt < 4; ++mt)
#pragma unroll
    for (int nt = 0; nt < 4; ++nt) acc[mt][nt] = (f32x4){0.f, 0.f, 0.f, 0.f};

  for (int kb = 0; kb < 4; ++kb) {
    const int koff = kb * 32 + kg * 8;
    short8v a[4];
#pragma unroll
    for (int mt = 0; mt < 4; ++mt)
      a[mt] = *(const short8v*)(xl + (mt * 16 + rlo) * 264 + koff);
#pragma unroll
    for (int nt = 0; nt < 4; ++nt) {
      short8v b = *(const short8v*)(Wbf + (((size_t)(wv * 4 + nt) * 4 + kb) * 64 + lane) * 8);
#pragma unroll
      for (int mt = 0; mt < 4; ++mt)
        acc[mt][nt] = __builtin_amdgcn_mfma_f32_16x16x32_bf16(a[mt], b, acc[mt][nt], 0, 0, 0);
    }
  }

  __syncthreads();   // all MFMA reads done before output overwrites xl

#pragma unroll
  for (int nt = 0; nt < 4; ++nt) {
    int u = cb + nt * 16 + rlo;
    float bias = (u < 128) ? msgb[u] : 0.0f;
#pragma unroll
    for (int mt = 0; mt < 4; ++mt)
#pragma unroll
      for (int r = 0; r < 4; ++r)
        xl[(mt * 16 + kg * 4 + r) * 264 + u] = f2bf(acc[mt][nt][r] + bias);
  }
  __syncthreads();

  const int row = t >> 2, seg = t & 3;
#pragma unroll
  for (int p = 0; p < 2; ++p) {
    const unsigned short* src = xl + row * 264 + p * 128 + seg * 32;
    unsigned short* dst = (p ? P2 : P1) + (size_t)(n0 + row) * 128 + seg * 32;
    *(uint4*)(dst)      = *(const uint4*)(src);
    *(uint4*)(dst + 8)  = *(const uint4*)(src + 8);
    *(uint4*)(dst + 16) = *(const uint4*)(src + 16);
    *(uint4*)(dst + 24) = *(const uint4*)(src + 24);
  }
}

// ---------------------------------------------------------------------------
// agg (CSR, bf16 in/out): wave per node v, lane = 2 channels. 8-deep unroll.
// ---------------------------------------------------------------------------
__global__ __launch_bounds__(256) void agg_kernel(
    const unsigned short* __restrict__ P1, const unsigned short* __restrict__ P2,
    const int* __restrict__ offs, const int* __restrict__ adj,
    unsigned short* __restrict__ aggb)
{
  const int v = blockIdx.x * 4 + (threadIdx.x >> 6);
  const int lane = threadIdx.x & 63;
  unsigned int p1 = *(const unsigned int*)(P1 + (size_t)v * 128 + lane * 2);
  const float p1x = bf2f(p1 & 0xFFFFu), p1y = bf2f(p1 >> 16);
  float sx = 0.f, sy = 0.f;
  const int beg = offs[v], end = offs[v + 1];
  int j = beg;
  for (; j + 8 <= end; j += 8) {
    unsigned int q[8];
#pragma unroll
    for (int i = 0; i < 8; ++i) {
      int u = adj[j + i];
      q[i] = *(const unsigned int*)(P2 + (size_t)u * 128 + lane * 2);
    }
#pragma unroll
    for (int i = 0; i < 8; ++i) {
      sx += fmaxf(p1x + bf2f(q[i] & 0xFFFFu), 0.f);
      sy += fmaxf(p1y + bf2f(q[i] >> 16), 0.f);
    }
  }
  for (; j + 4 <= end; j += 4) {
    unsigned int q[4];
#pragma unroll
    for (int i = 0; i < 4; ++i) {
      int u = adj[j + i];
      q[i] = *(const unsigned int*)(P2 + (size_t)u * 128 + lane * 2);
    }
#pragma unroll
    for (int i = 0; i < 4; ++i) {
      sx += fmaxf(p1x + bf2f(q[i] & 0xFFFFu), 0.f);
      sy += fmaxf(p1y + bf2f(q[i] >> 16), 0.f);
    }
  }
  for (; j < end; ++j) {
    int u = adj[j];
    unsigned int q = *(const unsigned int*)(P2 + (size_t)u * 128 + lane * 2);
    sx += fmaxf(p1x + bf2f(q & 0xFFFFu), 0.f);
    sy += fmaxf(p1y + bf2f(q >> 16), 0.f);
  }
  *(unsigned int*)(aggb + (size_t)v * 128 + lane * 2) = pack2(sx, sy);
}

// ---------------------------------------------------------------------------
// GRU core (device inline), SINGLE-PASS, PACKED weights:
// At (256,2) the full 128-acc single pass fits the 256-reg budget without
// spill (R18's VGPR=128 showed packed addressing cut arch-reg demand).
// Halves LDS A-fragment reads vs the R12 two-pass. 64-node tile, stride 264.
// ---------------------------------------------------------------------------
__device__ __forceinline__ void gru_core(
    unsigned short* xl, int t,
    const unsigned short* __restrict__ aggb, const unsigned short* __restrict__ hin,
    const unsigned short* __restrict__ wrz, const unsigned short* __restrict__ wni,
    const unsigned short* __restrict__ wnh,
    const float* __restrict__ bih, const float* __restrict__ bhh, int n0)
{
  const int lane = t & 63, wv = t >> 6;

#pragma unroll
  for (int i = 0; i < 8; ++i) {
    int id = t + 256 * i;
    int row = (id >> 4) & 63, ch = id & 15;
    const unsigned short* src = (i < 4) ? aggb : hin;
    int cb0 = (i < 4) ? 0 : 128;
    *(uint4*)(xl + row * 264 + cb0 + ch * 8) =
        *(const uint4*)(src + (size_t)(n0 + row) * 128 + ch * 8);
  }
  __syncthreads();

  const int rlo = lane & 15, kg = lane >> 4;
  const int cb = wv * 32;

  f32x4 ar[4][2], az[4][2], ain[4][2], ahn[4][2];
#pragma unroll
  for (int mt = 0; mt < 4; ++mt)
#pragma unroll
    for (int nt = 0; nt < 2; ++nt) {
      ar[mt][nt] = (f32x4){0,0,0,0}; az[mt][nt] = (f32x4){0,0,0,0};
      ain[mt][nt] = (f32x4){0,0,0,0}; ahn[mt][nt] = (f32x4){0,0,0,0};
    }

#pragma unroll
  for (int kb = 0; kb < 8; ++kb) {
    const int koff = kb * 32 + kg * 8;        // [0,256)
    short8v a[4];
#pragma unroll
    for (int mt = 0; mt < 4; ++mt)
      a[mt] = *(const short8v*)(xl + (mt * 16 + rlo) * 264 + koff);
#pragma unroll
    for (int nt = 0; nt < 2; ++nt) {
      const int ct = wv * 2 + nt;             // r-gate ctile; z = ct + 8
      short8v br = *(const short8v*)(wrz + (((size_t)ct * 8 + kb) * 64 + lane) * 8);
      short8v bz = *(const short8v*)(wrz + (((size_t)(ct + 8) * 8 + kb) * 64 + lane) * 8);
#pragma unroll
      for (int mt = 0; mt < 4; ++mt) {
        ar[mt][nt] = __builtin_amdgcn_mfma_f32_16x16x32_bf16(a[mt], br, ar[mt][nt], 0, 0, 0);
        az[mt][nt] = __builtin_amdgcn_mfma_f32_16x16x32_bf16(a[mt], bz, az[mt][nt], 0, 0, 0);
      }
      if (kb < 4) {
        short8v bi = *(const short8v*)(wni + (((size_t)ct * 4 + kb) * 64 + lane) * 8);
#pragma unroll
        for (int mt = 0; mt < 4; ++mt)
          ain[mt][nt] = __builtin_amdgcn_mfma_f32_16x16x32_bf16(a[mt], bi, ain[mt][nt], 0, 0, 0);
      } else {
        short8v bh = *(const short8v*)(wnh + (((size_t)ct * 4 + (kb - 4)) * 64 + lane) * 8);
#pragma unroll
        for (int mt = 0; mt < 4; ++mt)
          ahn[mt][nt] = __builtin_amdgcn_mfma_f32_16x16x32_bf16(a[mt], bh, ahn[mt][nt], 0, 0, 0);
      }
    }
  }

  __syncthreads();   // all MFMA reads done before transpose writes

#pragma unroll
  for (int nt = 0; nt < 2; ++nt) {
    const int c = cb + nt * 16 + rlo;
    const float brz_r = bih[c] + bhh[c];
    const float brz_z = bih[128 + c] + bhh[128 + c];
    const float b_in = bih[256 + c], b_hn = bhh[256 + c];
#pragma unroll
    for (int mt = 0; mt < 4; ++mt)
#pragma unroll
      for (int r = 0; r < 4; ++r) {
        const int nl = mt * 16 + kg * 4 + r;
        float hv = bf2f(xl[nl * 264 + 128 + c]);
        float rg = sigf(ar[mt][nt][r] + brz_r);
        float zz = sigf(az[mt][nt][r] + brz_z);
        float nn = tanhfast(ain[mt][nt][r] + b_in + rg * (ahn[mt][nt][r] + b_hn));
        xl[nl * 264 + c] = f2bf((1.0f - zz) * nn + zz * hv);
      }
  }
  __syncthreads();
}

// ---------------------------------------------------------------------------
// Fused gru(l=0) + proj(l=1): hn -> hnb (bf16) and P1/P2 for the next layer.
// ---------------------------------------------------------------------------
__global__ __launch_bounds__(256, 2) void gru_proj_kernel(
    const unsigned short* __restrict__ aggb, const unsigned short* __restrict__ hin,
    const unsigned short* __restrict__ wrz, const unsigned short* __restrict__ wni,
    const unsigned short* __restrict__ wnh,
    const float* __restrict__ bih, const float* __restrict__ bhh,
    const unsigned short* __restrict__ Wm, const float* __restrict__ msgb,
    unsigned short* __restrict__ hout,
    unsigned short* __restrict__ P1, unsigned short* __restrict__ P2)
{
  __shared__ unsigned short xl[64 * 264];
  const int t = threadIdx.x, lane = t & 63, wv = t >> 6;
  const int n0 = blockIdx.x * 64;

  gru_core(xl, t, aggb, hin, wrz, wni, wnh, bih, bhh, n0);

  // store hn (bf16) from LDS cols [0,128)
  {
    const int row = t >> 2, seg = t & 3;
    const unsigned short* src = xl + row * 264 + seg * 32;
    unsigned short* dst = hout + (size_t)(n0 + row) * 128 + seg * 32;
    *(uint4*)(dst)      = *(const uint4*)(src);
    *(uint4*)(dst + 8)  = *(const uint4*)(src + 8);
    *(uint4*)(dst + 16) = *(const uint4*)(src + 16);
    *(uint4*)(dst + 24) = *(const uint4*)(src + 24);
  }

  // proj phase on the in-LDS hn (cols [0,128))
  const int cb = wv * 64;
  const int rlo = lane & 15, kg = lane >> 4;
  f32x4 acc[4][4];
#pragma unroll
  for (int mt = 0; mt < 4; ++mt)
#pragma unroll
    for (int nt = 0; nt < 4; ++nt) acc[mt][nt] = (f32x4){0.f, 0.f, 0.f, 0.f};

  for (int kb = 0; kb < 4; ++kb) {
    const int koff = kb * 32 + kg * 8;
    short8v a[4];
#pragma unroll
    for (int mt = 0; mt < 4; ++mt)
      a[mt] = *(const short8v*)(xl + (mt * 16 + rlo) * 264 + koff);
#pragma unroll
    for (int nt = 0; nt < 4; ++nt) {
      short8v b = *(const short8v*)(Wm + (((size_t)(wv * 4 + nt) * 4 + kb) * 64 + lane) * 8);
#pragma unroll
      for (int mt = 0; mt < 4; ++mt)
        acc[mt][nt] = __builtin_amdgcn_mfma_f32_16x16x32_bf16(a[mt], b, acc[mt][nt], 0, 0, 0);
    }
  }

  __syncthreads();   // all proj MFMA reads done before output overwrites xl

#pragma unroll
  for (int nt = 0; nt < 4; ++nt) {
    int u = cb + nt * 16 + rlo;
    float bias = (u < 128) ? msgb[u] : 0.0f;
#pragma unroll
    for (int mt = 0; mt < 4; ++mt)
#pragma unroll
      for (int r = 0; r < 4; ++r)
        xl[(mt * 16 + kg * 4 + r) * 264 + u] = f2bf(acc[mt][nt][r] + bias);
  }
  __syncthreads();

  const int row = t >> 2, seg = t & 3;
#pragma unroll
  for (int p = 0; p < 2; ++p) {
    const unsigned short* src = xl + row * 264 + p * 128 + seg * 32;
    unsigned short* dst = (p ? P2 : P1) + (size_t)(n0 + row) * 128 + seg * 32;
    *(uint4*)(dst)      = *(const uint4*)(src);
    *(uint4*)(dst + 8)  = *(const uint4*)(src + 8);
    *(uint4*)(dst + 16) = *(const uint4*)(src + 16);
    *(uint4*)(dst + 24) = *(const uint4*)(src + 24);
  }
}

// ---------------------------------------------------------------------------
// Fused gru(l=1) + gated readout: out_hn (f32) + hG/hGi (2 graphs per block).
// ---------------------------------------------------------------------------
__global__ __launch_bounds__(256, 2) void gru_gated_kernel(
    const unsigned short* __restrict__ aggb, const unsigned short* __restrict__ hin,
    const unsigned short* __restrict__ wrz, const unsigned short* __restrict__ wni,
    const unsigned short* __restrict__ wnh,
    const float* __restrict__ bih, const float* __restrict__ bhh,
    const unsigned short* __restrict__ wcat,
    const float* __restrict__ fmb,  const float* __restrict__ gmW,
    const float* __restrict__ gmb,  const float* __restrict__ fmib,
    const float* __restrict__ gmiW, const float* __restrict__ gmib,
    float* __restrict__ out_hn, float* __restrict__ hG, float* __restrict__ hGi)
{
  __shared__ unsigned short xl[64 * 264];
  __shared__ float g_lds[2][64];
  __shared__ float sg_lds[2][2];
  const int t = threadIdx.x, lane = t & 63, wv = t >> 6;
  const int n0 = blockIdx.x * 64;

  gru_core(xl, t, aggb, hin, wrz, wni, wnh, bih, bhh, n0);

  // store out_hn (widened f32) from LDS cols [0,128)
  {
    const int row = t >> 2, seg = t & 3;
    const unsigned short* src = xl + row * 264 + seg * 32;
    float* dst = out_hn + (size_t)(n0 + row) * 128 + seg * 32;
#pragma unroll
    for (int q = 0; q < 8; ++q) {
      float4 v;
      v.x = bf2f(src[q * 4 + 0]); v.y = bf2f(src[q * 4 + 1]);
      v.z = bf2f(src[q * 4 + 2]); v.w = bf2f(src[q * 4 + 3]);
      *(float4*)(dst + q * 4) = v;
    }
  }

  // gate dots on in-LDS hn
  if (t < 128) {
    int node = t & 63, head = t >> 6;
    const float* gw = head ? gmiW : gmW;
    float s = 0.0f;
    for (int k = 0; k < 128; ++k)
      s = fmaf(bf2f(xl[node * 264 + k]), gw[k], s);
    s += head ? gmib[0] : gmb[0];
    g_lds[head][node] = sigf(s);
  }
  __syncthreads();
  if (t < 4) {
    int head = t >> 1, gr = t & 1;
    float s = 0.0f;
    for (int i = 0; i < 32; ++i) s += g_lds[head][gr * 32 + i];
    sg_lds[head][gr] = s;
  }
  __syncthreads();

  // Y = hn @ wcat.T  (128 fused channels: 64 fm + 64 fmi)
  const int rlo = lane & 15, kg = lane >> 4;
  const int cb = wv * 32;
  f32x4 acc[4][2];
#pragma unroll
  for (int mt = 0; mt < 4; ++mt)
#pragma unroll
    for (int nt = 0; nt < 2; ++nt) acc[mt][nt] = (f32x4){0.f, 0.f, 0.f, 0.f};

  for (int kb = 0; kb < 4; ++kb) {
    const int koff = kb * 32 + kg * 8;
    short8v a[4];
#pragma unroll
    for (int mt = 0; mt < 4; ++mt)
      a[mt] = *(const short8v*)(xl + (mt * 16 + rlo) * 264 + koff);
#pragma unroll
    for (int nt = 0; nt < 2; ++nt) {
      const int ct = wv * 2 + nt;
      short8v b = *(const short8v*)(wcat + (((size_t)ct * 4 + kb) * 64 + lane) * 8);
#pragma unroll
      for (int mt = 0; mt < 4; ++mt)
        acc[mt][nt] = __builtin_amdgcn_mfma_f32_16x16x32_bf16(a[mt], b, acc[mt][nt], 0, 0, 0);
    }
  }

#pragma unroll
  for (int nt = 0; nt < 2; ++nt) {
    const int ch = cb + nt * 16 + rlo;       // [0,128), head uniform per wave
    const int head = ch >> 6, s = ch & 63;
    const float fbv = head ? fmib[s] : fmb[s];
    float pA = 0.f, pB = 0.f;
#pragma unroll
    for (int mt = 0; mt < 2; ++mt)
#pragma unroll
      for (int r = 0; r < 4; ++r) {
        pA += g_lds[head][mt * 16 + kg * 4 + r]       * acc[mt][nt][r];
        pB += g_lds[head][(mt + 2) * 16 + kg * 4 + r] * acc[mt + 2][nt][r];
      }
    pA += __shfl_xor(pA, 16); pA += __shfl_xor(pA, 32);
    pB += __shfl_xor(pB, 16); pB += __shfl_xor(pB, 32);
    if (kg == 0) {
      float* dst = head ? hGi : hG;
      dst[(size_t)(blockIdx.x * 2)     * 64 + s] = pA + fbv * sg_lds[head][0];
      dst[(size_t)(blockIdx.x * 2 + 1) * 64 + s] = pB + fbv * sg_lds[head][1];
    }
  }
}

// ---------------------------------------------------------------------------
extern "C" void kernel_launch(void* const* d_in, const int* in_sizes, int n_in,
                              void* d_out, int out_size, void* d_ws, size_t ws_size,
                              hipStream_t stream)
{
  (void)in_sizes; (void)n_in; (void)out_size; (void)ws_size;

  const float* h    = (const float*)d_in[0];
  const float* msgW = (const float*)d_in[1];
  const float* msgb = (const float*)d_in[2];
  const float* Wih  = (const float*)d_in[3];
  const float* Whh  = (const float*)d_in[4];
  const float* bih  = (const float*)d_in[5];
  const float* bhh  = (const float*)d_in[6];
  const float* fmW  = (const float*)d_in[7];
  const float* fmb  = (const float*)d_in[8];
  const float* gmW  = (const float*)d_in[9];
  const float* gmb  = (const float*)d_in[10];
  const float* fmiW = (const float*)d_in[11];
  const float* fmib = (const float*)d_in[12];
  const float* gmiW = (const float*)d_in[13];
  const float* gmib = (const float*)d_in[14];
  const int*   ei   = (const int*)d_in[15];
  const int* e0 = ei;
  const int* e1 = ei + EDGES;

  // ---- workspace carve ----
  char* w = (char*)d_ws;
  const size_t NF = (size_t)NNODE * NDIM_;
  unsigned short* P1b  = (unsigned short*)w;  w += NF * 2;
  unsigned short* P2b  = (unsigned short*)w;  w += NF * 2;
  unsigned short* aggb = (unsigned short*)w;  w += NF * 2;
  unsigned short* hb   = (unsigned short*)w;  w += NF * 2;
  unsigned short* hnb  = (unsigned short*)w;  w += NF * 2;
  int* cnt  = (int*)w;                        w += (size_t)NNODE * 4;
  int* offs = (int*)w;                        w += (size_t)(NNODE + 64) * 4;
  int* cur  = (int*)w;                        w += (size_t)NNODE * 4;
  int* adj  = (int*)w;                        w += (size_t)2 * EDGES * 4;
  int* bsum = (int*)w;                        w += 256 * 4;
  int* boff = (int*)w;                        w += 256 * 4;
  unsigned short* wm   = (unsigned short*)w;  w += (size_t)2 * 256 * 128 * 2;
  unsigned short* wrz  = (unsigned short*)w;  w += (size_t)2 * 256 * 256 * 2;
  unsigned short* wni  = (unsigned short*)w;  w += (size_t)2 * 128 * 128 * 2;
  unsigned short* wnh  = (unsigned short*)w;  w += (size_t)2 * 128 * 128 * 2;
  unsigned short* wcat = (unsigned short*)w;  w += (size_t)128 * 128 * 2;

  float* out_hn  = (float*)d_out;
  float* out_hG  = out_hn + NF;
  float* out_hGi = out_hG + (size_t)B_ * SDIM_;

  // ---- one-time: conversions (+cnt zero) + CSR ----
  convert_all_kernel<<<(int)(NF / 8 / 256), 256, 0, stream>>>(
      h, msgW, Wih, Whh, fmW, fmiW, hb, wm, wrz, wni, wnh, wcat, cnt);
  hist_kernel<<<EDGES / 256, 256, 0, stream>>>(e0, e1, cnt);
  scan1_kernel<<<NNODE / 256, 256, 0, stream>>>(cnt, offs, bsum);
  scan2_kernel<<<1, 256, 0, stream>>>(bsum, boff);
  scan3_kernel<<<NNODE / 256, 256, 0, stream>>>(cnt, offs, boff, cur);
  scatter_kernel<<<EDGES / 256, 256, 0, stream>>>(e0, e1, cur, adj);

  // ---- layer 0 ----
  proj_mfma_kernel<<<NNODE / 64, 256, 0, stream>>>(hb, wm, msgb, P1b, P2b);
  agg_kernel<<<NNODE / 4, 256, 0, stream>>>(P1b, P2b, offs, adj, aggb);
  gru_proj_kernel<<<NNODE / 64, 256, 0, stream>>>(
      aggb, hb, wrz, wni, wnh, bih, bhh,
      wm + (size_t)256 * 128, msgb + 128, hnb, P1b, P2b);

  // ---- layer 1 + readout ----
  agg_kernel<<<NNODE / 4, 256, 0, stream>>>(P1b, P2b, offs, adj, aggb);
  gru_gated_kernel<<<NNODE / 64, 256, 0, stream>>>(
      aggb, hnb,
      wrz + (size_t)256 * 256, wni + (size_t)128 * 128, wnh + (size_t)128 * 128,
      bih + 384, bhh + 384,
      wcat, fmb, gmW, gmb, fmib, gmiW, gmib,
      out_hn, out_hG, out_hGi);
}

// Round 20
// 226.692 us; speedup vs baseline: 1.0299x; 1.0299x over previous
//
#include <hip/hip_runtime.h>

typedef float f32x4 __attribute__((ext_vector_type(4)));
typedef short short8v __attribute__((ext_vector_type(8)));

#define B_    2048
#define IDX_  32
#define NDIM_ 128
#define SDIM_ 64
#define EDGES 262144
#define NNODE 65536   // B_*32

__device__ __forceinline__ float fastrcp(float x) { return __builtin_amdgcn_rcpf(x); }
__device__ __forceinline__ float sigf(float x) { return fastrcp(1.0f + __expf(-x)); }
__device__ __forceinline__ float tanhfast(float x) {
  return 1.0f - 2.0f * fastrcp(1.0f + __expf(2.0f * x));
}

__device__ __forceinline__ unsigned short f2bf(float f) {        // RNE
  unsigned int u = __float_as_uint(f);
  return (unsigned short)((u + 0x7FFFu + ((u >> 16) & 1u)) >> 16);
}
__device__ __forceinline__ float bf2f(unsigned int h) {
  return __uint_as_float(h << 16);
}
__device__ __forceinline__ unsigned int pack2(float a, float b) {
  return (unsigned int)f2bf(a) | ((unsigned int)f2bf(b) << 16);
}

// ---------------------------------------------------------------------------
// one-time conversions. All weight buffers are packed into MFMA-FRAGMENT
// order [ctile][kb][lane][8]: lane l supplies B-row (ct*16 + (l&15)) elems
// k = kb*32 + (l>>4)*8 .. +8. A wave's fragment load is then one coalesced
// 1KB burst instead of a 16-line gather.
// ---------------------------------------------------------------------------
__global__ __launch_bounds__(256) void convert_all_kernel(
    const float* __restrict__ h,    const float* __restrict__ msgW,
    const float* __restrict__ Wih,  const float* __restrict__ Whh,
    const float* __restrict__ fmW,  const float* __restrict__ fmiW,
    unsigned short* __restrict__ hb,
    unsigned short* __restrict__ wm, unsigned short* __restrict__ wrz,
    unsigned short* __restrict__ wni, unsigned short* __restrict__ wnh,
    unsigned short* __restrict__ wcat, int* __restrict__ cnt)
{
  int id = blockIdx.x * 256 + threadIdx.x;       // [0, 1048576)
  if (id < 2 * 256 * 256) {                      // wrzP: 256 ch x 256 k, 2 layers
    int l = id >> 16, pid = id & 65535;
    int e = pid & 7, lane = (pid >> 3) & 63, kb = (pid >> 9) & 7, ct = pid >> 12;
    int c = ct * 16 + (lane & 15);
    int k = kb * 32 + (lane >> 4) * 8 + e;
    const float* base = (k < 128) ? Wih : Whh;
    wrz[id] = f2bf(base[(size_t)l * 384 * 128 + (size_t)c * 128 + (k & 127)]);
  }
  if (id < 2 * 256 * 128) {                      // wmP: 256 vch x 128 k, 2 layers
    int l = id >> 15, pid = id & 32767;
    int e = pid & 7, lane = (pid >> 3) & 63, kb = (pid >> 9) & 3, ct = pid >> 11;
    int u = ct * 16 + (lane & 15);
    int k = kb * 32 + (lane >> 4) * 8 + e;
    wm[id] = f2bf(msgW[(size_t)l * 128 * 256 + (size_t)(u & 127) * 256
                       + ((u >> 7) << 7) + k]);
  }
  if (id < 2 * 128 * 128) {                      // wniP / wnhP: 128 ch x 128 k
    int l = id >> 14, pid = id & 16383;
    int e = pid & 7, lane = (pid >> 3) & 63, kb = (pid >> 9) & 3, ct = pid >> 11;
    int c = ct * 16 + (lane & 15);
    int k = kb * 32 + (lane >> 4) * 8 + e;
    size_t src = (size_t)l * 384 * 128 + (size_t)(256 + c) * 128 + k;
    wni[id] = f2bf(Wih[src]);
    wnh[id] = f2bf(Whh[src]);
  }
  if (id < 128 * 128) {                          // wcatP: 128 ch x 128 k
    int pid = id;
    int e = pid & 7, lane = (pid >> 3) & 63, kb = (pid >> 9) & 3, ct = pid >> 11;
    int c = ct * 16 + (lane & 15);
    int k = kb * 32 + (lane >> 4) * 8 + e;
    wcat[id] = f2bf(c < 64 ? fmW[(size_t)c * 128 + k]
                           : fmiW[(size_t)(c - 64) * 128 + k]);
  }
  if (id < NNODE) cnt[id] = 0;
  {
    size_t i = (size_t)id * 8;
    float4 a = *(const float4*)(h + i);
    float4 b = *(const float4*)(h + i + 4);
    uint4 o;
    o.x = pack2(a.x, a.y); o.y = pack2(a.z, a.w);
    o.z = pack2(b.x, b.y); o.w = pack2(b.z, b.w);
    *(uint4*)(hb + i) = o;
  }
}

// ---------------------------------------------------------------------------
// CSR build: hist -> 3-phase scan -> scatter
// ---------------------------------------------------------------------------
__global__ __launch_bounds__(256) void hist_kernel(
    const int* __restrict__ e0, const int* __restrict__ e1, int* __restrict__ cnt)
{
  int e = blockIdx.x * 256 + threadIdx.x;
  if (e < EDGES) {
    atomicAdd(&cnt[e1[e]], 1);
    atomicAdd(&cnt[e0[e]], 1);
  }
}

__global__ __launch_bounds__(256) void scan1_kernel(
    const int* __restrict__ cnt, int* __restrict__ offs, int* __restrict__ bsum)
{
  __shared__ int sh[256];
  const int t = threadIdx.x;
  const int i = blockIdx.x * 256 + t;
  int v = cnt[i];
  int x = v;
  sh[t] = x;
  __syncthreads();
#pragma unroll
  for (int off = 1; off < 256; off <<= 1) {
    int y = (t >= off) ? sh[t - off] : 0;
    __syncthreads();
    x += y; sh[t] = x;
    __syncthreads();
  }
  offs[i] = x - v;
  if (t == 255) bsum[blockIdx.x] = x;
}

__global__ __launch_bounds__(256) void scan2_kernel(int* __restrict__ bsum,
                                                    int* __restrict__ boff)
{
  __shared__ int sh[256];
  const int t = threadIdx.x;
  int v = bsum[t];
  int x = v;
  sh[t] = x;
  __syncthreads();
#pragma unroll
  for (int off = 1; off < 256; off <<= 1) {
    int y = (t >= off) ? sh[t - off] : 0;
    __syncthreads();
    x += y; sh[t] = x;
    __syncthreads();
  }
  boff[t] = x - v;
}

__global__ __launch_bounds__(256) void scan3_kernel(
    const int* __restrict__ cnt, int* __restrict__ offs,
    const int* __restrict__ boff, int* __restrict__ cur)
{
  const int i = blockIdx.x * 256 + threadIdx.x;
  int o = offs[i] + boff[blockIdx.x];
  offs[i] = o; cur[i] = o;
  if (i == NNODE - 1) offs[NNODE] = o + cnt[i];
}

__global__ __launch_bounds__(256) void scatter_kernel(
    const int* __restrict__ e0, const int* __restrict__ e1,
    int* __restrict__ cur, int* __restrict__ adj)
{
  int e = blockIdx.x * 256 + threadIdx.x;
  if (e < EDGES) {
    int a = e0[e], b = e1[e];
    int p = atomicAdd(&cur[b], 1); adj[p] = a;
    int q = atomicAdd(&cur[a], 1); adj[q] = b;
  }
}

// ---------------------------------------------------------------------------
// proj (MFMA, 64-node tiles, single LDS buffer, packed weights):
// P1 = hn@W1.T + msgb, P2 = hn@W2.T.
// ---------------------------------------------------------------------------
__global__ __launch_bounds__(256, 3) void proj_mfma_kernel(
    const unsigned short* __restrict__ hb, const unsigned short* __restrict__ Wbf,
    const float* __restrict__ msgb,
    unsigned short* __restrict__ P1, unsigned short* __restrict__ P2)
{
  __shared__ unsigned short xl[64 * 264];
  const int t = threadIdx.x, lane = t & 63, wv = t >> 6;
  const int n0 = blockIdx.x * 64;

#pragma unroll
  for (int i = 0; i < 4; ++i) {
    int id = t + 256 * i;
    int row = id >> 4, ch = id & 15;
    *(uint4*)(xl + row * 264 + ch * 8) =
        *(const uint4*)(hb + (size_t)(n0 + row) * 128 + ch * 8);
  }
  __syncthreads();

  const int cb = wv * 64;
  const int rlo = lane & 15;
  const int kg  = lane >> 4;
  f32x4 acc[4][4];
#pragma unroll
  for (int mt = 0; mt < 4; ++mt)
#pragma unroll
    for (int nt = 0; nt < 4; ++nt) acc[mt][nt] = (f32x4){0.f, 0.f, 0.f, 0.f};

  for (int kb = 0; kb < 4; ++kb) {
    const int koff = kb * 32 + kg * 8;
    short8v a[4];
#pragma unroll
    for (int mt = 0; mt < 4; ++mt)
      a[mt] = *(const short8v*)(xl + (mt * 16 + rlo) * 264 + koff);
#pragma unroll
    for (int nt = 0; nt < 4; ++nt) {
      short8v b = *(const short8v*)(Wbf + (((size_t)(wv * 4 + nt) * 4 + kb) * 64 + lane) * 8);
#pragma unroll
      for (int mt = 0; mt < 4; ++mt)
        acc[mt][nt] = __builtin_amdgcn_mfma_f32_16x16x32_bf16(a[mt], b, acc[mt][nt], 0, 0, 0);
    }
  }

  __syncthreads();   // all MFMA reads done before output overwrites xl

#pragma unroll
  for (int nt = 0; nt < 4; ++nt) {
    int u = cb + nt * 16 + rlo;
    float bias = (u < 128) ? msgb[u] : 0.0f;
#pragma unroll
    for (int mt = 0; mt < 4; ++mt)
#pragma unroll
      for (int r = 0; r < 4; ++r)
        xl[(mt * 16 + kg * 4 + r) * 264 + u] = f2bf(acc[mt][nt][r] + bias);
  }
  __syncthreads();

  const int row = t >> 2, seg = t & 3;
#pragma unroll
  for (int p = 0; p < 2; ++p) {
    const unsigned short* src = xl + row * 264 + p * 128 + seg * 32;
    unsigned short* dst = (p ? P2 : P1) + (size_t)(n0 + row) * 128 + seg * 32;
    *(uint4*)(dst)      = *(const uint4*)(src);
    *(uint4*)(dst + 8)  = *(const uint4*)(src + 8);
    *(uint4*)(dst + 16) = *(const uint4*)(src + 16);
    *(uint4*)(dst + 24) = *(const uint4*)(src + 24);
  }
}

// ---------------------------------------------------------------------------
// agg (CSR, bf16 in/out): wave per node v, lane = 2 channels. 8-deep unroll.
// ---------------------------------------------------------------------------
__global__ __launch_bounds__(256) void agg_kernel(
    const unsigned short* __restrict__ P1, const unsigned short* __restrict__ P2,
    const int* __restrict__ offs, const int* __restrict__ adj,
    unsigned short* __restrict__ aggb)
{
  const int v = blockIdx.x * 4 + (threadIdx.x >> 6);
  const int lane = threadIdx.x & 63;
  unsigned int p1 = *(const unsigned int*)(P1 + (size_t)v * 128 + lane * 2);
  const float p1x = bf2f(p1 & 0xFFFFu), p1y = bf2f(p1 >> 16);
  float sx = 0.f, sy = 0.f;
  const int beg = offs[v], end = offs[v + 1];
  int j = beg;
  for (; j + 8 <= end; j += 8) {
    unsigned int q[8];
#pragma unroll
    for (int i = 0; i < 8; ++i) {
      int u = adj[j + i];
      q[i] = *(const unsigned int*)(P2 + (size_t)u * 128 + lane * 2);
    }
#pragma unroll
    for (int i = 0; i < 8; ++i) {
      sx += fmaxf(p1x + bf2f(q[i] & 0xFFFFu), 0.f);
      sy += fmaxf(p1y + bf2f(q[i] >> 16), 0.f);
    }
  }
  for (; j + 4 <= end; j += 4) {
    unsigned int q[4];
#pragma unroll
    for (int i = 0; i < 4; ++i) {
      int u = adj[j + i];
      q[i] = *(const unsigned int*)(P2 + (size_t)u * 128 + lane * 2);
    }
#pragma unroll
    for (int i = 0; i < 4; ++i) {
      sx += fmaxf(p1x + bf2f(q[i] & 0xFFFFu), 0.f);
      sy += fmaxf(p1y + bf2f(q[i] >> 16), 0.f);
    }
  }
  for (; j < end; ++j) {
    int u = adj[j];
    unsigned int q = *(const unsigned int*)(P2 + (size_t)u * 128 + lane * 2);
    sx += fmaxf(p1x + bf2f(q & 0xFFFFu), 0.f);
    sy += fmaxf(p1y + bf2f(q >> 16), 0.f);
  }
  *(unsigned int*)(aggb + (size_t)v * 128 + lane * 2) = pack2(sx, sy);
}

// ---------------------------------------------------------------------------
// GRU core (device inline), TWO-PASS, PACKED weights (R18 config — measured
// best: two-pass phase diversity + (256,2) no-spill):
//   pass 1: r/z gates over K=256 (64 acc regs) -> rg,zz packed bf16
//   pass 2: n gate (ain/ahn, 64 acc regs) -> final combine.
// 64-node tile, xl stride 264.
// ---------------------------------------------------------------------------
__device__ __forceinline__ void gru_core(
    unsigned short* xl, int t,
    const unsigned short* __restrict__ aggb, const unsigned short* __restrict__ hin,
    const unsigned short* __restrict__ wrz, const unsigned short* __restrict__ wni,
    const unsigned short* __restrict__ wnh,
    const float* __restrict__ bih, const float* __restrict__ bhh, int n0)
{
  const int lane = t & 63, wv = t >> 6;

#pragma unroll
  for (int i = 0; i < 8; ++i) {
    int id = t + 256 * i;
    int row = (id >> 4) & 63, ch = id & 15;
    const unsigned short* src = (i < 4) ? aggb : hin;
    int cb0 = (i < 4) ? 0 : 128;
    *(uint4*)(xl + row * 264 + cb0 + ch * 8) =
        *(const uint4*)(src + (size_t)(n0 + row) * 128 + ch * 8);
  }
  __syncthreads();

  const int rlo = lane & 15, kg = lane >> 4;
  const int cb = wv * 32;

  // ---- pass 1: r and z gates (K = 256 fused) ----
  unsigned int rgzz[4][2][4];                 // packed (rg, zz) bf16 pairs
  {
    f32x4 ar[4][2], az[4][2];
#pragma unroll
    for (int mt = 0; mt < 4; ++mt)
#pragma unroll
      for (int nt = 0; nt < 2; ++nt) {
        ar[mt][nt] = (f32x4){0,0,0,0}; az[mt][nt] = (f32x4){0,0,0,0};
      }

#pragma unroll
    for (int kb = 0; kb < 8; ++kb) {
      const int koff = kb * 32 + kg * 8;      // [0,256)
      short8v a[4];
#pragma unroll
      for (int mt = 0; mt < 4; ++mt)
        a[mt] = *(const short8v*)(xl + (mt * 16 + rlo) * 264 + koff);
#pragma unroll
      for (int nt = 0; nt < 2; ++nt) {
        const int ct = wv * 2 + nt;           // r-gate ctile; z = ct + 8
        short8v br = *(const short8v*)(wrz + (((size_t)ct * 8 + kb) * 64 + lane) * 8);
        short8v bz = *(const short8v*)(wrz + (((size_t)(ct + 8) * 8 + kb) * 64 + lane) * 8);
#pragma unroll
        for (int mt = 0; mt < 4; ++mt) {
          ar[mt][nt] = __builtin_amdgcn_mfma_f32_16x16x32_bf16(a[mt], br, ar[mt][nt], 0, 0, 0);
          az[mt][nt] = __builtin_amdgcn_mfma_f32_16x16x32_bf16(a[mt], bz, az[mt][nt], 0, 0, 0);
        }
      }
    }

#pragma unroll
    for (int nt = 0; nt < 2; ++nt) {
      const int c = cb + nt * 16 + rlo;
      const float brz_r = bih[c] + bhh[c];
      const float brz_z = bih[128 + c] + bhh[128 + c];
#pragma unroll
      for (int mt = 0; mt < 4; ++mt)
#pragma unroll
        for (int r = 0; r < 4; ++r) {
          float rg = sigf(ar[mt][nt][r] + brz_r);
          float zz = sigf(az[mt][nt][r] + brz_z);
          rgzz[mt][nt][r] = pack2(rg, zz);
        }
    }
  }
  __builtin_amdgcn_sched_barrier(0);          // keep pass 1 regs dead here

  // ---- pass 2: n gate ----
  {
    f32x4 ain[4][2], ahn[4][2];
#pragma unroll
    for (int mt = 0; mt < 4; ++mt)
#pragma unroll
      for (int nt = 0; nt < 2; ++nt) {
        ain[mt][nt] = (f32x4){0,0,0,0}; ahn[mt][nt] = (f32x4){0,0,0,0};
      }

#pragma unroll
    for (int kb = 0; kb < 8; ++kb) {
      const int koff = kb * 32 + kg * 8;      // [0,256)
      short8v a[4];
#pragma unroll
      for (int mt = 0; mt < 4; ++mt)
        a[mt] = *(const short8v*)(xl + (mt * 16 + rlo) * 264 + koff);
#pragma unroll
      for (int nt = 0; nt < 2; ++nt) {
        const int ct = wv * 2 + nt;
        if (kb < 4) {
          short8v bi = *(const short8v*)(wni + (((size_t)ct * 4 + kb) * 64 + lane) * 8);
#pragma unroll
          for (int mt = 0; mt < 4; ++mt)
            ain[mt][nt] = __builtin_amdgcn_mfma_f32_16x16x32_bf16(a[mt], bi, ain[mt][nt], 0, 0, 0);
        } else {
          short8v bh = *(const short8v*)(wnh + (((size_t)ct * 4 + (kb - 4)) * 64 + lane) * 8);
#pragma unroll
          for (int mt = 0; mt < 4; ++mt)
            ahn[mt][nt] = __builtin_amdgcn_mfma_f32_16x16x32_bf16(a[mt], bh, ahn[mt][nt], 0, 0, 0);
        }
      }
    }

    __syncthreads();   // all MFMA reads done before transpose writes

#pragma unroll
    for (int nt = 0; nt < 2; ++nt) {
      const int c = cb + nt * 16 + rlo;
      const float b_in = bih[256 + c], b_hn = bhh[256 + c];
#pragma unroll
      for (int mt = 0; mt < 4; ++mt)
#pragma unroll
        for (int r = 0; r < 4; ++r) {
          const int nl = mt * 16 + kg * 4 + r;
          float hv = bf2f(xl[nl * 264 + 128 + c]);
          float rg = bf2f(rgzz[mt][nt][r] & 0xFFFFu);
          float zz = bf2f(rgzz[mt][nt][r] >> 16);
          float nn = tanhfast(ain[mt][nt][r] + b_in + rg * (ahn[mt][nt][r] + b_hn));
          xl[nl * 264 + c] = f2bf((1.0f - zz) * nn + zz * hv);
        }
    }
  }
  __syncthreads();
}

// ---------------------------------------------------------------------------
// Fused gru(l=0) + proj(l=1): hn -> hnb (bf16) and P1/P2 for the next layer.
// ---------------------------------------------------------------------------
__global__ __launch_bounds__(256, 2) void gru_proj_kernel(
    const unsigned short* __restrict__ aggb, const unsigned short* __restrict__ hin,
    const unsigned short* __restrict__ wrz, const unsigned short* __restrict__ wni,
    const unsigned short* __restrict__ wnh,
    const float* __restrict__ bih, const float* __restrict__ bhh,
    const unsigned short* __restrict__ Wm, const float* __restrict__ msgb,
    unsigned short* __restrict__ hout,
    unsigned short* __restrict__ P1, unsigned short* __restrict__ P2)
{
  __shared__ unsigned short xl[64 * 264];
  const int t = threadIdx.x, lane = t & 63, wv = t >> 6;
  const int n0 = blockIdx.x * 64;

  gru_core(xl, t, aggb, hin, wrz, wni, wnh, bih, bhh, n0);

  // store hn (bf16) from LDS cols [0,128)
  {
    const int row = t >> 2, seg = t & 3;
    const unsigned short* src = xl + row * 264 + seg * 32;
    unsigned short* dst = hout + (size_t)(n0 + row) * 128 + seg * 32;
    *(uint4*)(dst)      = *(const uint4*)(src);
    *(uint4*)(dst + 8)  = *(const uint4*)(src + 8);
    *(uint4*)(dst + 16) = *(const uint4*)(src + 16);
    *(uint4*)(dst + 24) = *(const uint4*)(src + 24);
  }

  // proj phase on the in-LDS hn (cols [0,128))
  const int cb = wv * 64;
  const int rlo = lane & 15, kg = lane >> 4;
  f32x4 acc[4][4];
#pragma unroll
  for (int mt = 0; mt < 4; ++mt)
#pragma unroll
    for (int nt = 0; nt < 4; ++nt) acc[mt][nt] = (f32x4){0.f, 0.f, 0.f, 0.f};

  for (int kb = 0; kb < 4; ++kb) {
    const int koff = kb * 32 + kg * 8;
    short8v a[4];
#pragma unroll
    for (int mt = 0; mt < 4; ++mt)
      a[mt] = *(const short8v*)(xl + (mt * 16 + rlo) * 264 + koff);
#pragma unroll
    for (int nt = 0; nt < 4; ++nt) {
      short8v b = *(const short8v*)(Wm + (((size_t)(wv * 4 + nt) * 4 + kb) * 64 + lane) * 8);
#pragma unroll
      for (int mt = 0; mt < 4; ++mt)
        acc[mt][nt] = __builtin_amdgcn_mfma_f32_16x16x32_bf16(a[mt], b, acc[mt][nt], 0, 0, 0);
    }
  }

  __syncthreads();   // all proj MFMA reads done before output overwrites xl

#pragma unroll
  for (int nt = 0; nt < 4; ++nt) {
    int u = cb + nt * 16 + rlo;
    float bias = (u < 128) ? msgb[u] : 0.0f;
#pragma unroll
    for (int mt = 0; mt < 4; ++mt)
#pragma unroll
      for (int r = 0; r < 4; ++r)
        xl[(mt * 16 + kg * 4 + r) * 264 + u] = f2bf(acc[mt][nt][r] + bias);
  }
  __syncthreads();

  const int row = t >> 2, seg = t & 3;
#pragma unroll
  for (int p = 0; p < 2; ++p) {
    const unsigned short* src = xl + row * 264 + p * 128 + seg * 32;
    unsigned short* dst = (p ? P2 : P1) + (size_t)(n0 + row) * 128 + seg * 32;
    *(uint4*)(dst)      = *(const uint4*)(src);
    *(uint4*)(dst + 8)  = *(const uint4*)(src + 8);
    *(uint4*)(dst + 16) = *(const uint4*)(src + 16);
    *(uint4*)(dst + 24) = *(const uint4*)(src + 24);
  }
}

// ---------------------------------------------------------------------------
// Fused gru(l=1) + gated readout: out_hn (f32) + hG/hGi (2 graphs per block).
// Gate dots wave-parallelized: 2 threads per (head,node), uint (2-ch) reads.
// ---------------------------------------------------------------------------
__global__ __launch_bounds__(256, 2) void gru_gated_kernel(
    const unsigned short* __restrict__ aggb, const unsigned short* __restrict__ hin,
    const unsigned short* __restrict__ wrz, const unsigned short* __restrict__ wni,
    const unsigned short* __restrict__ wnh,
    const float* __restrict__ bih, const float* __restrict__ bhh,
    const unsigned short* __restrict__ wcat,
    const float* __restrict__ fmb,  const float* __restrict__ gmW,
    const float* __restrict__ gmb,  const float* __restrict__ fmib,
    const float* __restrict__ gmiW, const float* __restrict__ gmib,
    float* __restrict__ out_hn, float* __restrict__ hG, float* __restrict__ hGi)
{
  __shared__ unsigned short xl[64 * 264];
  __shared__ float g_lds[2][64];
  __shared__ float sg_lds[2][2];
  const int t = threadIdx.x, lane = t & 63, wv = t >> 6;
  const int n0 = blockIdx.x * 64;

  gru_core(xl, t, aggb, hin, wrz, wni, wnh, bih, bhh, n0);

  // store out_hn (widened f32) from LDS cols [0,128)
  {
    const int row = t >> 2, seg = t & 3;
    const unsigned short* src = xl + row * 264 + seg * 32;
    float* dst = out_hn + (size_t)(n0 + row) * 128 + seg * 32;
#pragma unroll
    for (int q = 0; q < 8; ++q) {
      float4 v;
      v.x = bf2f(src[q * 4 + 0]); v.y = bf2f(src[q * 4 + 1]);
      v.z = bf2f(src[q * 4 + 2]); v.w = bf2f(src[q * 4 + 3]);
      *(float4*)(dst + q * 4) = v;
    }
  }

  // gate dots on in-LDS hn: task = (head, node), 2 threads per task,
  // each sums 64 channels via 32 uint (2-ch) reads, combine via shfl.
  {
    const int task = t >> 1;                 // 0..127
    const int sub  = t & 1;                  // channel half
    const int node = task & 63, head = task >> 6;
    const float* gw = head ? gmiW : gmW;
    const unsigned short* hrow = xl + node * 264 + sub * 64;
    const float* gww = gw + sub * 64;
    float s = 0.0f;
#pragma unroll
    for (int k2 = 0; k2 < 32; ++k2) {
      unsigned int pr = *(const unsigned int*)(hrow + k2 * 2);
      s = fmaf(bf2f(pr & 0xFFFFu), gww[k2 * 2], s);
      s = fmaf(bf2f(pr >> 16),     gww[k2 * 2 + 1], s);
    }
    s += __shfl_xor(s, 1);
    if (sub == 0)
      g_lds[head][node] = sigf(s + (head ? gmib[0] : gmb[0]));
  }
  __syncthreads();
  if (t < 4) {
    int head = t >> 1, gr = t & 1;
    float s = 0.0f;
    for (int i = 0; i < 32; ++i) s += g_lds[head][gr * 32 + i];
    sg_lds[head][gr] = s;
  }
  __syncthreads();

  // Y = hn @ wcat.T  (128 fused channels: 64 fm + 64 fmi)
  const int rlo = lane & 15, kg = lane >> 4;
  const int cb = wv * 32;
  f32x4 acc[4][2];
#pragma unroll
  for (int mt = 0; mt < 4; ++mt)
#pragma unroll
    for (int nt = 0; nt < 2; ++nt) acc[mt][nt] = (f32x4){0.f, 0.f, 0.f, 0.f};

  for (int kb = 0; kb < 4; ++kb) {
    const int koff = kb * 32 + kg * 8;
    short8v a[4];
#pragma unroll
    for (int mt = 0; mt < 4; ++mt)
      a[mt] = *(const short8v*)(xl + (mt * 16 + rlo) * 264 + koff);
#pragma unroll
    for (int nt = 0; nt < 2; ++nt) {
      const int ct = wv * 2 + nt;
      short8v b = *(const short8v*)(wcat + (((size_t)ct * 4 + kb) * 64 + lane) * 8);
#pragma unroll
      for (int mt = 0; mt < 4; ++mt)
        acc[mt][nt] = __builtin_amdgcn_mfma_f32_16x16x32_bf16(a[mt], b, acc[mt][nt], 0, 0, 0);
    }
  }

#pragma unroll
  for (int nt = 0; nt < 2; ++nt) {
    const int ch = cb + nt * 16 + rlo;       // [0,128), head uniform per wave
    const int head = ch >> 6, s = ch & 63;
    const float fbv = head ? fmib[s] : fmb[s];
    float pA = 0.f, pB = 0.f;
#pragma unroll
    for (int mt = 0; mt < 2; ++mt)
#pragma unroll
      for (int r = 0; r < 4; ++r) {
        pA += g_lds[head][mt * 16 + kg * 4 + r]       * acc[mt][nt][r];
        pB += g_lds[head][(mt + 2) * 16 + kg * 4 + r] * acc[mt + 2][nt][r];
      }
    pA += __shfl_xor(pA, 16); pA += __shfl_xor(pA, 32);
    pB += __shfl_xor(pB, 16); pB += __shfl_xor(pB, 32);
    if (kg == 0) {
      float* dst = head ? hGi : hG;
      dst[(size_t)(blockIdx.x * 2)     * 64 + s] = pA + fbv * sg_lds[head][0];
      dst[(size_t)(blockIdx.x * 2 + 1) * 64 + s] = pB + fbv * sg_lds[head][1];
    }
  }
}

// ---------------------------------------------------------------------------
extern "C" void kernel_launch(void* const* d_in, const int* in_sizes, int n_in,
                              void* d_out, int out_size, void* d_ws, size_t ws_size,
                              hipStream_t stream)
{
  (void)in_sizes; (void)n_in; (void)out_size; (void)ws_size;

  const float* h    = (const float*)d_in[0];
  const float* msgW = (const float*)d_in[1];
  const float* msgb = (const float*)d_in[2];
  const float* Wih  = (const float*)d_in[3];
  const float* Whh  = (const float*)d_in[4];
  const float* bih  = (const float*)d_in[5];
  const float* bhh  = (const float*)d_in[6];
  const float* fmW  = (const float*)d_in[7];
  const float* fmb  = (const float*)d_in[8];
  const float* gmW  = (const float*)d_in[9];
  const float* gmb  = (const float*)d_in[10];
  const float* fmiW = (const float*)d_in[11];
  const float* fmib = (const float*)d_in[12];
  const float* gmiW = (const float*)d_in[13];
  const float* gmib = (const float*)d_in[14];
  const int*   ei   = (const int*)d_in[15];
  const int* e0 = ei;
  const int* e1 = ei + EDGES;

  // ---- workspace carve ----
  char* w = (char*)d_ws;
  const size_t NF = (size_t)NNODE * NDIM_;
  unsigned short* P1b  = (unsigned short*)w;  w += NF * 2;
  unsigned short* P2b  = (unsigned short*)w;  w += NF * 2;
  unsigned short* aggb = (unsigned short*)w;  w += NF * 2;
  unsigned short* hb   = (unsigned short*)w;  w += NF * 2;
  unsigned short* hnb  = (unsigned short*)w;  w += NF * 2;
  int* cnt  = (int*)w;                        w += (size_t)NNODE * 4;
  int* offs = (int*)w;                        w += (size_t)(NNODE + 64) * 4;
  int* cur  = (int*)w;                        w += (size_t)NNODE * 4;
  int* adj  = (int*)w;                        w += (size_t)2 * EDGES * 4;
  int* bsum = (int*)w;                        w += 256 * 4;
  int* boff = (int*)w;                        w += 256 * 4;
  unsigned short* wm   = (unsigned short*)w;  w += (size_t)2 * 256 * 128 * 2;
  unsigned short* wrz  = (unsigned short*)w;  w += (size_t)2 * 256 * 256 * 2;
  unsigned short* wni  = (unsigned short*)w;  w += (size_t)2 * 128 * 128 * 2;
  unsigned short* wnh  = (unsigned short*)w;  w += (size_t)2 * 128 * 128 * 2;
  unsigned short* wcat = (unsigned short*)w;  w += (size_t)128 * 128 * 2;

  float* out_hn  = (float*)d_out;
  float* out_hG  = out_hn + NF;
  float* out_hGi = out_hG + (size_t)B_ * SDIM_;

  // ---- one-time: conversions (+cnt zero) + CSR ----
  convert_all_kernel<<<(int)(NF / 8 / 256), 256, 0, stream>>>(
      h, msgW, Wih, Whh, fmW, fmiW, hb, wm, wrz, wni, wnh, wcat, cnt);
  hist_kernel<<<EDGES / 256, 256, 0, stream>>>(e0, e1, cnt);
  scan1_kernel<<<NNODE / 256, 256, 0, stream>>>(cnt, offs, bsum);
  scan2_kernel<<<1, 256, 0, stream>>>(bsum, boff);
  scan3_kernel<<<NNODE / 256, 256, 0, stream>>>(cnt, offs, boff, cur);
  scatter_kernel<<<EDGES / 256, 256, 0, stream>>>(e0, e1, cur, adj);

  // ---- layer 0 ----
  proj_mfma_kernel<<<NNODE / 64, 256, 0, stream>>>(hb, wm, msgb, P1b, P2b);
  agg_kernel<<<NNODE / 4, 256, 0, stream>>>(P1b, P2b, offs, adj, aggb);
  gru_proj_kernel<<<NNODE / 64, 256, 0, stream>>>(
      aggb, hb, wrz, wni, wnh, bih, bhh,
      wm + (size_t)256 * 128, msgb + 128, hnb, P1b, P2b);

  // ---- layer 1 + readout ----
  agg_kernel<<<NNODE / 4, 256, 0, stream>>>(P1b, P2b, offs, adj, aggb);
  gru_gated_kernel<<<NNODE / 64, 256, 0, stream>>>(
      aggb, hnb,
      wrz + (size_t)256 * 256, wni + (size_t)128 * 128, wnh + (size_t)128 * 128,
      bih + 384, bhh + 384,
      wcat, fmb, gmW, gmb, fmib, gmiW, gmib,
      out_hn, out_hG, out_hGi);
}

// Round 21
// 214.672 us; speedup vs baseline: 1.0876x; 1.0560x over previous
//
#include <hip/hip_runtime.h>

typedef float f32x4 __attribute__((ext_vector_type(4)));
typedef float f32x2 __attribute__((ext_vector_type(2)));
typedef short short8v __attribute__((ext_vector_type(8)));

#define B_    2048
#define IDX_  32
#define NDIM_ 128
#define SDIM_ 64
#define EDGES 262144
#define NNODE 65536   // B_*32

__device__ __forceinline__ float fastrcp(float x) { return __builtin_amdgcn_rcpf(x); }
__device__ __forceinline__ float sigf(float x) { return fastrcp(1.0f + __expf(-x)); }
__device__ __forceinline__ float tanhfast(float x) {
  return 1.0f - 2.0f * fastrcp(1.0f + __expf(2.0f * x));
}

__device__ __forceinline__ unsigned short f2bf(float f) {        // RNE
  unsigned int u = __float_as_uint(f);
  return (unsigned short)((u + 0x7FFFu + ((u >> 16) & 1u)) >> 16);
}
__device__ __forceinline__ float bf2f(unsigned int h) {
  return __uint_as_float(h << 16);
}
__device__ __forceinline__ unsigned int pack2(float a, float b) {
  return (unsigned int)f2bf(a) | ((unsigned int)f2bf(b) << 16);
}
// pack 4 floats -> 4 OCP e4m3 bytes (HW cvt, RNE)
__device__ __forceinline__ unsigned int pk_fp8x4(float f0, float f1, float f2, float f3) {
  int w = 0;
  w = __builtin_amdgcn_cvt_pk_fp8_f32(f0, f1, w, false);
  w = __builtin_amdgcn_cvt_pk_fp8_f32(f2, f3, w, true);
  return (unsigned int)w;
}

// ---------------------------------------------------------------------------
// one-time conversions. Weight buffers packed into MFMA-FRAGMENT order
// [ctile][kb][lane][8] (coalesced 1KB wave bursts).
// ---------------------------------------------------------------------------
__global__ __launch_bounds__(256) void convert_all_kernel(
    const float* __restrict__ h,    const float* __restrict__ msgW,
    const float* __restrict__ Wih,  const float* __restrict__ Whh,
    const float* __restrict__ fmW,  const float* __restrict__ fmiW,
    unsigned short* __restrict__ hb,
    unsigned short* __restrict__ wm, unsigned short* __restrict__ wrz,
    unsigned short* __restrict__ wni, unsigned short* __restrict__ wnh,
    unsigned short* __restrict__ wcat, int* __restrict__ cnt)
{
  int id = blockIdx.x * 256 + threadIdx.x;       // [0, 1048576)
  if (id < 2 * 256 * 256) {                      // wrzP: 256 ch x 256 k, 2 layers
    int l = id >> 16, pid = id & 65535;
    int e = pid & 7, lane = (pid >> 3) & 63, kb = (pid >> 9) & 7, ct = pid >> 12;
    int c = ct * 16 + (lane & 15);
    int k = kb * 32 + (lane >> 4) * 8 + e;
    const float* base = (k < 128) ? Wih : Whh;
    wrz[id] = f2bf(base[(size_t)l * 384 * 128 + (size_t)c * 128 + (k & 127)]);
  }
  if (id < 2 * 256 * 128) {                      // wmP: 256 vch x 128 k, 2 layers
    int l = id >> 15, pid = id & 32767;
    int e = pid & 7, lane = (pid >> 3) & 63, kb = (pid >> 9) & 3, ct = pid >> 11;
    int u = ct * 16 + (lane & 15);
    int k = kb * 32 + (lane >> 4) * 8 + e;
    wm[id] = f2bf(msgW[(size_t)l * 128 * 256 + (size_t)(u & 127) * 256
                       + ((u >> 7) << 7) + k]);
  }
  if (id < 2 * 128 * 128) {                      // wniP / wnhP: 128 ch x 128 k
    int l = id >> 14, pid = id & 16383;
    int e = pid & 7, lane = (pid >> 3) & 63, kb = (pid >> 9) & 3, ct = pid >> 11;
    int c = ct * 16 + (lane & 15);
    int k = kb * 32 + (lane >> 4) * 8 + e;
    size_t src = (size_t)l * 384 * 128 + (size_t)(256 + c) * 128 + k;
    wni[id] = f2bf(Wih[src]);
    wnh[id] = f2bf(Whh[src]);
  }
  if (id < 128 * 128) {                          // wcatP: 128 ch x 128 k
    int pid = id;
    int e = pid & 7, lane = (pid >> 3) & 63, kb = (pid >> 9) & 3, ct = pid >> 11;
    int c = ct * 16 + (lane & 15);
    int k = kb * 32 + (lane >> 4) * 8 + e;
    wcat[id] = f2bf(c < 64 ? fmW[(size_t)c * 128 + k]
                           : fmiW[(size_t)(c - 64) * 128 + k]);
  }
  if (id < NNODE) cnt[id] = 0;
  {
    size_t i = (size_t)id * 8;
    float4 a = *(const float4*)(h + i);
    float4 b = *(const float4*)(h + i + 4);
    uint4 o;
    o.x = pack2(a.x, a.y); o.y = pack2(a.z, a.w);
    o.z = pack2(b.x, b.y); o.w = pack2(b.z, b.w);
    *(uint4*)(hb + i) = o;
  }
}

// ---------------------------------------------------------------------------
// CSR build: hist -> 3-phase scan -> scatter
// ---------------------------------------------------------------------------
__global__ __launch_bounds__(256) void hist_kernel(
    const int* __restrict__ e0, const int* __restrict__ e1, int* __restrict__ cnt)
{
  int e = blockIdx.x * 256 + threadIdx.x;
  if (e < EDGES) {
    atomicAdd(&cnt[e1[e]], 1);
    atomicAdd(&cnt[e0[e]], 1);
  }
}

__global__ __launch_bounds__(256) void scan1_kernel(
    const int* __restrict__ cnt, int* __restrict__ offs, int* __restrict__ bsum)
{
  __shared__ int sh[256];
  const int t = threadIdx.x;
  const int i = blockIdx.x * 256 + t;
  int v = cnt[i];
  int x = v;
  sh[t] = x;
  __syncthreads();
#pragma unroll
  for (int off = 1; off < 256; off <<= 1) {
    int y = (t >= off) ? sh[t - off] : 0;
    __syncthreads();
    x += y; sh[t] = x;
    __syncthreads();
  }
  offs[i] = x - v;
  if (t == 255) bsum[blockIdx.x] = x;
}

__global__ __launch_bounds__(256) void scan2_kernel(int* __restrict__ bsum,
                                                    int* __restrict__ boff)
{
  __shared__ int sh[256];
  const int t = threadIdx.x;
  int v = bsum[t];
  int x = v;
  sh[t] = x;
  __syncthreads();
#pragma unroll
  for (int off = 1; off < 256; off <<= 1) {
    int y = (t >= off) ? sh[t - off] : 0;
    __syncthreads();
    x += y; sh[t] = x;
    __syncthreads();
  }
  boff[t] = x - v;
}

__global__ __launch_bounds__(256) void scan3_kernel(
    const int* __restrict__ cnt, int* __restrict__ offs,
    const int* __restrict__ boff, int* __restrict__ cur)
{
  const int i = blockIdx.x * 256 + threadIdx.x;
  int o = offs[i] + boff[blockIdx.x];
  offs[i] = o; cur[i] = o;
  if (i == NNODE - 1) offs[NNODE] = o + cnt[i];
}

__global__ __launch_bounds__(256) void scatter_kernel(
    const int* __restrict__ e0, const int* __restrict__ e1,
    int* __restrict__ cur, int* __restrict__ adj)
{
  int e = blockIdx.x * 256 + threadIdx.x;
  if (e < EDGES) {
    int a = e0[e], b = e1[e];
    int p = atomicAdd(&cur[b], 1); adj[p] = a;
    int q = atomicAdd(&cur[a], 1); adj[q] = b;
  }
}

// ---------------------------------------------------------------------------
// proj (MFMA, 64-node tiles, packed weights): P1 (bf16) = hn@W1.T + msgb,
// P2 (fp8 e4m3) = hn@W2.T — fp8 halves the agg gather row to one 128B line.
// ---------------------------------------------------------------------------
__global__ __launch_bounds__(256, 3) void proj_mfma_kernel(
    const unsigned short* __restrict__ hb, const unsigned short* __restrict__ Wbf,
    const float* __restrict__ msgb,
    unsigned short* __restrict__ P1, unsigned char* __restrict__ P2)
{
  __shared__ unsigned short xl[64 * 264];
  const int t = threadIdx.x, lane = t & 63, wv = t >> 6;
  const int n0 = blockIdx.x * 64;

#pragma unroll
  for (int i = 0; i < 4; ++i) {
    int id = t + 256 * i;
    int row = id >> 4, ch = id & 15;
    *(uint4*)(xl + row * 264 + ch * 8) =
        *(const uint4*)(hb + (size_t)(n0 + row) * 128 + ch * 8);
  }
  __syncthreads();

  const int cb = wv * 64;
  const int rlo = lane & 15;
  const int kg  = lane >> 4;
  f32x4 acc[4][4];
#pragma unroll
  for (int mt = 0; mt < 4; ++mt)
#pragma unroll
    for (int nt = 0; nt < 4; ++nt) acc[mt][nt] = (f32x4){0.f, 0.f, 0.f, 0.f};

  for (int kb = 0; kb < 4; ++kb) {
    const int koff = kb * 32 + kg * 8;
    short8v a[4];
#pragma unroll
    for (int mt = 0; mt < 4; ++mt)
      a[mt] = *(const short8v*)(xl + (mt * 16 + rlo) * 264 + koff);
#pragma unroll
    for (int nt = 0; nt < 4; ++nt) {
      short8v b = *(const short8v*)(Wbf + (((size_t)(wv * 4 + nt) * 4 + kb) * 64 + lane) * 8);
#pragma unroll
      for (int mt = 0; mt < 4; ++mt)
        acc[mt][nt] = __builtin_amdgcn_mfma_f32_16x16x32_bf16(a[mt], b, acc[mt][nt], 0, 0, 0);
    }
  }

  __syncthreads();   // all MFMA reads done before output overwrites xl

#pragma unroll
  for (int nt = 0; nt < 4; ++nt) {
    int u = cb + nt * 16 + rlo;
    float bias = (u < 128) ? msgb[u] : 0.0f;
#pragma unroll
    for (int mt = 0; mt < 4; ++mt)
#pragma unroll
      for (int r = 0; r < 4; ++r)
        xl[(mt * 16 + kg * 4 + r) * 264 + u] = f2bf(acc[mt][nt][r] + bias);
  }
  __syncthreads();

  const int row = t >> 2, seg = t & 3;
  {  // P1 half: bf16, 64B per thread
    const unsigned short* src = xl + row * 264 + seg * 32;
    unsigned short* dst = P1 + (size_t)(n0 + row) * 128 + seg * 32;
    *(uint4*)(dst)      = *(const uint4*)(src);
    *(uint4*)(dst + 8)  = *(const uint4*)(src + 8);
    *(uint4*)(dst + 16) = *(const uint4*)(src + 16);
    *(uint4*)(dst + 24) = *(const uint4*)(src + 24);
  }
  {  // P2 half: fp8, 32B per thread
    const unsigned short* src = xl + row * 264 + 128 + seg * 32;
    unsigned int w[8];
#pragma unroll
    for (int q = 0; q < 8; ++q)
      w[q] = pk_fp8x4(bf2f(src[q * 4 + 0]), bf2f(src[q * 4 + 1]),
                      bf2f(src[q * 4 + 2]), bf2f(src[q * 4 + 3]));
    unsigned char* dst = P2 + (size_t)(n0 + row) * 128 + seg * 32;
    uint4 lo; lo.x = w[0]; lo.y = w[1]; lo.z = w[2]; lo.w = w[3];
    uint4 hi; hi.x = w[4]; hi.y = w[5]; hi.z = w[6]; hi.w = w[7];
    *(uint4*)(dst)      = lo;
    *(uint4*)(dst + 16) = hi;
  }
}

// ---------------------------------------------------------------------------
// agg (CSR): wave per node v, lane = 2 channels. P2 rows are fp8 (128B/row —
// one cache line per gather). 8-deep unroll.
// ---------------------------------------------------------------------------
__global__ __launch_bounds__(256) void agg_kernel(
    const unsigned short* __restrict__ P1, const unsigned char* __restrict__ P2,
    const int* __restrict__ offs, const int* __restrict__ adj,
    unsigned short* __restrict__ aggb)
{
  const int v = blockIdx.x * 4 + (threadIdx.x >> 6);
  const int lane = threadIdx.x & 63;
  unsigned int p1 = *(const unsigned int*)(P1 + (size_t)v * 128 + lane * 2);
  const float p1x = bf2f(p1 & 0xFFFFu), p1y = bf2f(p1 >> 16);
  float sx = 0.f, sy = 0.f;
  const int beg = offs[v], end = offs[v + 1];
  int j = beg;
  for (; j + 8 <= end; j += 8) {
    unsigned short q[8];
#pragma unroll
    for (int i = 0; i < 8; ++i) {
      int u = adj[j + i];
      q[i] = *(const unsigned short*)(P2 + (size_t)u * 128 + lane * 2);
    }
#pragma unroll
    for (int i = 0; i < 8; ++i) {
      f32x2 d = __builtin_amdgcn_cvt_pk_f32_fp8((int)q[i], false);
      sx += fmaxf(p1x + d.x, 0.f);
      sy += fmaxf(p1y + d.y, 0.f);
    }
  }
  for (; j + 4 <= end; j += 4) {
    unsigned short q[4];
#pragma unroll
    for (int i = 0; i < 4; ++i) {
      int u = adj[j + i];
      q[i] = *(const unsigned short*)(P2 + (size_t)u * 128 + lane * 2);
    }
#pragma unroll
    for (int i = 0; i < 4; ++i) {
      f32x2 d = __builtin_amdgcn_cvt_pk_f32_fp8((int)q[i], false);
      sx += fmaxf(p1x + d.x, 0.f);
      sy += fmaxf(p1y + d.y, 0.f);
    }
  }
  for (; j < end; ++j) {
    int u = adj[j];
    unsigned short qq = *(const unsigned short*)(P2 + (size_t)u * 128 + lane * 2);
    f32x2 d = __builtin_amdgcn_cvt_pk_f32_fp8((int)qq, false);
    sx += fmaxf(p1x + d.x, 0.f);
    sy += fmaxf(p1y + d.y, 0.f);
  }
  *(unsigned int*)(aggb + (size_t)v * 128 + lane * 2) = pack2(sx, sy);
}

// ---------------------------------------------------------------------------
// GRU core (device inline), TWO-PASS, PACKED weights (R18/R20 config):
//   pass 1: r/z gates over K=256 (64 acc regs) -> rg,zz packed bf16
//   pass 2: n gate (ain/ahn, 64 acc regs) -> final combine.
// 64-node tile, xl stride 264. Callers: (256,2), no spill.
// ---------------------------------------------------------------------------
__device__ __forceinline__ void gru_core(
    unsigned short* xl, int t,
    const unsigned short* __restrict__ aggb, const unsigned short* __restrict__ hin,
    const unsigned short* __restrict__ wrz, const unsigned short* __restrict__ wni,
    const unsigned short* __restrict__ wnh,
    const float* __restrict__ bih, const float* __restrict__ bhh, int n0)
{
  const int lane = t & 63, wv = t >> 6;

#pragma unroll
  for (int i = 0; i < 8; ++i) {
    int id = t + 256 * i;
    int row = (id >> 4) & 63, ch = id & 15;
    const unsigned short* src = (i < 4) ? aggb : hin;
    int cb0 = (i < 4) ? 0 : 128;
    *(uint4*)(xl + row * 264 + cb0 + ch * 8) =
        *(const uint4*)(src + (size_t)(n0 + row) * 128 + ch * 8);
  }
  __syncthreads();

  const int rlo = lane & 15, kg = lane >> 4;
  const int cb = wv * 32;

  // ---- pass 1: r and z gates (K = 256 fused) ----
  unsigned int rgzz[4][2][4];                 // packed (rg, zz) bf16 pairs
  {
    f32x4 ar[4][2], az[4][2];
#pragma unroll
    for (int mt = 0; mt < 4; ++mt)
#pragma unroll
      for (int nt = 0; nt < 2; ++nt) {
        ar[mt][nt] = (f32x4){0,0,0,0}; az[mt][nt] = (f32x4){0,0,0,0};
      }

#pragma unroll
    for (int kb = 0; kb < 8; ++kb) {
      const int koff = kb * 32 + kg * 8;      // [0,256)
      short8v a[4];
#pragma unroll
      for (int mt = 0; mt < 4; ++mt)
        a[mt] = *(const short8v*)(xl + (mt * 16 + rlo) * 264 + koff);
#pragma unroll
      for (int nt = 0; nt < 2; ++nt) {
        const int ct = wv * 2 + nt;           // r-gate ctile; z = ct + 8
        short8v br = *(const short8v*)(wrz + (((size_t)ct * 8 + kb) * 64 + lane) * 8);
        short8v bz = *(const short8v*)(wrz + (((size_t)(ct + 8) * 8 + kb) * 64 + lane) * 8);
#pragma unroll
        for (int mt = 0; mt < 4; ++mt) {
          ar[mt][nt] = __builtin_amdgcn_mfma_f32_16x16x32_bf16(a[mt], br, ar[mt][nt], 0, 0, 0);
          az[mt][nt] = __builtin_amdgcn_mfma_f32_16x16x32_bf16(a[mt], bz, az[mt][nt], 0, 0, 0);
        }
      }
    }

#pragma unroll
    for (int nt = 0; nt < 2; ++nt) {
      const int c = cb + nt * 16 + rlo;
      const float brz_r = bih[c] + bhh[c];
      const float brz_z = bih[128 + c] + bhh[128 + c];
#pragma unroll
      for (int mt = 0; mt < 4; ++mt)
#pragma unroll
        for (int r = 0; r < 4; ++r) {
          float rg = sigf(ar[mt][nt][r] + brz_r);
          float zz = sigf(az[mt][nt][r] + brz_z);
          rgzz[mt][nt][r] = pack2(rg, zz);
        }
    }
  }
  __builtin_amdgcn_sched_barrier(0);          // keep pass 1 regs dead here

  // ---- pass 2: n gate ----
  {
    f32x4 ain[4][2], ahn[4][2];
#pragma unroll
    for (int mt = 0; mt < 4; ++mt)
#pragma unroll
      for (int nt = 0; nt < 2; ++nt) {
        ain[mt][nt] = (f32x4){0,0,0,0}; ahn[mt][nt] = (f32x4){0,0,0,0};
      }

#pragma unroll
    for (int kb = 0; kb < 8; ++kb) {
      const int koff = kb * 32 + kg * 8;      // [0,256)
      short8v a[4];
#pragma unroll
      for (int mt = 0; mt < 4; ++mt)
        a[mt] = *(const short8v*)(xl + (mt * 16 + rlo) * 264 + koff);
#pragma unroll
      for (int nt = 0; nt < 2; ++nt) {
        const int ct = wv * 2 + nt;
        if (kb < 4) {
          short8v bi = *(const short8v*)(wni + (((size_t)ct * 4 + kb) * 64 + lane) * 8);
#pragma unroll
          for (int mt = 0; mt < 4; ++mt)
            ain[mt][nt] = __builtin_amdgcn_mfma_f32_16x16x32_bf16(a[mt], bi, ain[mt][nt], 0, 0, 0);
        } else {
          short8v bh = *(const short8v*)(wnh + (((size_t)ct * 4 + (kb - 4)) * 64 + lane) * 8);
#pragma unroll
          for (int mt = 0; mt < 4; ++mt)
            ahn[mt][nt] = __builtin_amdgcn_mfma_f32_16x16x32_bf16(a[mt], bh, ahn[mt][nt], 0, 0, 0);
        }
      }
    }

    __syncthreads();   // all MFMA reads done before transpose writes

#pragma unroll
    for (int nt = 0; nt < 2; ++nt) {
      const int c = cb + nt * 16 + rlo;
      const float b_in = bih[256 + c], b_hn = bhh[256 + c];
#pragma unroll
      for (int mt = 0; mt < 4; ++mt)
#pragma unroll
        for (int r = 0; r < 4; ++r) {
          const int nl = mt * 16 + kg * 4 + r;
          float hv = bf2f(xl[nl * 264 + 128 + c]);
          float rg = bf2f(rgzz[mt][nt][r] & 0xFFFFu);
          float zz = bf2f(rgzz[mt][nt][r] >> 16);
          float nn = tanhfast(ain[mt][nt][r] + b_in + rg * (ahn[mt][nt][r] + b_hn));
          xl[nl * 264 + c] = f2bf((1.0f - zz) * nn + zz * hv);
        }
    }
  }
  __syncthreads();
}

// ---------------------------------------------------------------------------
// Fused gru(l=0) + proj(l=1): hn -> hnb (bf16), P1 (bf16) + P2 (fp8).
// ---------------------------------------------------------------------------
__global__ __launch_bounds__(256, 2) void gru_proj_kernel(
    const unsigned short* __restrict__ aggb, const unsigned short* __restrict__ hin,
    const unsigned short* __restrict__ wrz, const unsigned short* __restrict__ wni,
    const unsigned short* __restrict__ wnh,
    const float* __restrict__ bih, const float* __restrict__ bhh,
    const unsigned short* __restrict__ Wm, const float* __restrict__ msgb,
    unsigned short* __restrict__ hout,
    unsigned short* __restrict__ P1, unsigned char* __restrict__ P2)
{
  __shared__ unsigned short xl[64 * 264];
  const int t = threadIdx.x, lane = t & 63, wv = t >> 6;
  const int n0 = blockIdx.x * 64;

  gru_core(xl, t, aggb, hin, wrz, wni, wnh, bih, bhh, n0);

  // store hn (bf16) from LDS cols [0,128)
  {
    const int row = t >> 2, seg = t & 3;
    const unsigned short* src = xl + row * 264 + seg * 32;
    unsigned short* dst = hout + (size_t)(n0 + row) * 128 + seg * 32;
    *(uint4*)(dst)      = *(const uint4*)(src);
    *(uint4*)(dst + 8)  = *(const uint4*)(src + 8);
    *(uint4*)(dst + 16) = *(const uint4*)(src + 16);
    *(uint4*)(dst + 24) = *(const uint4*)(src + 24);
  }

  // proj phase on the in-LDS hn (cols [0,128))
  const int cb = wv * 64;
  const int rlo = lane & 15, kg = lane >> 4;
  f32x4 acc[4][4];
#pragma unroll
  for (int mt = 0; mt < 4; ++mt)
#pragma unroll
    for (int nt = 0; nt < 4; ++nt) acc[mt][nt] = (f32x4){0.f, 0.f, 0.f, 0.f};

  for (int kb = 0; kb < 4; ++kb) {
    const int koff = kb * 32 + kg * 8;
    short8v a[4];
#pragma unroll
    for (int mt = 0; mt < 4; ++mt)
      a[mt] = *(const short8v*)(xl + (mt * 16 + rlo) * 264 + koff);
#pragma unroll
    for (int nt = 0; nt < 4; ++nt) {
      short8v b = *(const short8v*)(Wm + (((size_t)(wv * 4 + nt) * 4 + kb) * 64 + lane) * 8);
#pragma unroll
      for (int mt = 0; mt < 4; ++mt)
        acc[mt][nt] = __builtin_amdgcn_mfma_f32_16x16x32_bf16(a[mt], b, acc[mt][nt], 0, 0, 0);
    }
  }

  __syncthreads();   // all proj MFMA reads done before output overwrites xl

#pragma unroll
  for (int nt = 0; nt < 4; ++nt) {
    int u = cb + nt * 16 + rlo;
    float bias = (u < 128) ? msgb[u] : 0.0f;
#pragma unroll
    for (int mt = 0; mt < 4; ++mt)
#pragma unroll
      for (int r = 0; r < 4; ++r)
        xl[(mt * 16 + kg * 4 + r) * 264 + u] = f2bf(acc[mt][nt][r] + bias);
  }
  __syncthreads();

  const int row = t >> 2, seg = t & 3;
  {  // P1 half: bf16
    const unsigned short* src = xl + row * 264 + seg * 32;
    unsigned short* dst = P1 + (size_t)(n0 + row) * 128 + seg * 32;
    *(uint4*)(dst)      = *(const uint4*)(src);
    *(uint4*)(dst + 8)  = *(const uint4*)(src + 8);
    *(uint4*)(dst + 16) = *(const uint4*)(src + 16);
    *(uint4*)(dst + 24) = *(const uint4*)(src + 24);
  }
  {  // P2 half: fp8
    const unsigned short* src = xl + row * 264 + 128 + seg * 32;
    unsigned int w[8];
#pragma unroll
    for (int q = 0; q < 8; ++q)
      w[q] = pk_fp8x4(bf2f(src[q * 4 + 0]), bf2f(src[q * 4 + 1]),
                      bf2f(src[q * 4 + 2]), bf2f(src[q * 4 + 3]));
    unsigned char* dst = P2 + (size_t)(n0 + row) * 128 + seg * 32;
    uint4 lo; lo.x = w[0]; lo.y = w[1]; lo.z = w[2]; lo.w = w[3];
    uint4 hi; hi.x = w[4]; hi.y = w[5]; hi.z = w[6]; hi.w = w[7];
    *(uint4*)(dst)      = lo;
    *(uint4*)(dst + 16) = hi;
  }
}

// ---------------------------------------------------------------------------
// Fused gru(l=1) + gated readout: out_hn (f32) + hG/hGi (2 graphs per block).
// ---------------------------------------------------------------------------
__global__ __launch_bounds__(256, 2) void gru_gated_kernel(
    const unsigned short* __restrict__ aggb, const unsigned short* __restrict__ hin,
    const unsigned short* __restrict__ wrz, const unsigned short* __restrict__ wni,
    const unsigned short* __restrict__ wnh,
    const float* __restrict__ bih, const float* __restrict__ bhh,
    const unsigned short* __restrict__ wcat,
    const float* __restrict__ fmb,  const float* __restrict__ gmW,
    const float* __restrict__ gmb,  const float* __restrict__ fmib,
    const float* __restrict__ gmiW, const float* __restrict__ gmib,
    float* __restrict__ out_hn, float* __restrict__ hG, float* __restrict__ hGi)
{
  __shared__ unsigned short xl[64 * 264];
  __shared__ float g_lds[2][64];
  __shared__ float sg_lds[2][2];
  const int t = threadIdx.x, lane = t & 63, wv = t >> 6;
  const int n0 = blockIdx.x * 64;

  gru_core(xl, t, aggb, hin, wrz, wni, wnh, bih, bhh, n0);

  // store out_hn (widened f32) from LDS cols [0,128)
  {
    const int row = t >> 2, seg = t & 3;
    const unsigned short* src = xl + row * 264 + seg * 32;
    float* dst = out_hn + (size_t)(n0 + row) * 128 + seg * 32;
#pragma unroll
    for (int q = 0; q < 8; ++q) {
      float4 v;
      v.x = bf2f(src[q * 4 + 0]); v.y = bf2f(src[q * 4 + 1]);
      v.z = bf2f(src[q * 4 + 2]); v.w = bf2f(src[q * 4 + 3]);
      *(float4*)(dst + q * 4) = v;
    }
  }

  // gate dots: 2 threads per (head,node), uint (2-ch) reads, shfl combine.
  {
    const int task = t >> 1;                 // 0..127
    const int sub  = t & 1;                  // channel half
    const int node = task & 63, head = task >> 6;
    const float* gw = head ? gmiW : gmW;
    const unsigned short* hrow = xl + node * 264 + sub * 64;
    const float* gww = gw + sub * 64;
    float s = 0.0f;
#pragma unroll
    for (int k2 = 0; k2 < 32; ++k2) {
      unsigned int pr = *(const unsigned int*)(hrow + k2 * 2);
      s = fmaf(bf2f(pr & 0xFFFFu), gww[k2 * 2], s);
      s = fmaf(bf2f(pr >> 16),     gww[k2 * 2 + 1], s);
    }
    s += __shfl_xor(s, 1);
    if (sub == 0)
      g_lds[head][node] = sigf(s + (head ? gmib[0] : gmb[0]));
  }
  __syncthreads();
  if (t < 4) {
    int head = t >> 1, gr = t & 1;
    float s = 0.0f;
    for (int i = 0; i < 32; ++i) s += g_lds[head][gr * 32 + i];
    sg_lds[head][gr] = s;
  }
  __syncthreads();

  // Y = hn @ wcat.T  (128 fused channels: 64 fm + 64 fmi)
  const int rlo = lane & 15, kg = lane >> 4;
  const int cb = wv * 32;
  f32x4 acc[4][2];
#pragma unroll
  for (int mt = 0; mt < 4; ++mt)
#pragma unroll
    for (int nt = 0; nt < 2; ++nt) acc[mt][nt] = (f32x4){0.f, 0.f, 0.f, 0.f};

  for (int kb = 0; kb < 4; ++kb) {
    const int koff = kb * 32 + kg * 8;
    short8v a[4];
#pragma unroll
    for (int mt = 0; mt < 4; ++mt)
      a[mt] = *(const short8v*)(xl + (mt * 16 + rlo) * 264 + koff);
#pragma unroll
    for (int nt = 0; nt < 2; ++nt) {
      const int ct = wv * 2 + nt;
      short8v b = *(const short8v*)(wcat + (((size_t)ct * 4 + kb) * 64 + lane) * 8);
#pragma unroll
      for (int mt = 0; mt < 4; ++mt)
        acc[mt][nt] = __builtin_amdgcn_mfma_f32_16x16x32_bf16(a[mt], b, acc[mt][nt], 0, 0, 0);
    }
  }

#pragma unroll
  for (int nt = 0; nt < 2; ++nt) {
    const int ch = cb + nt * 16 + rlo;       // [0,128), head uniform per wave
    const int head = ch >> 6, s = ch & 63;
    const float fbv = head ? fmib[s] : fmb[s];
    float pA = 0.f, pB = 0.f;
#pragma unroll
    for (int mt = 0; mt < 2; ++mt)
#pragma unroll
      for (int r = 0; r < 4; ++r) {
        pA += g_lds[head][mt * 16 + kg * 4 + r]       * acc[mt][nt][r];
        pB += g_lds[head][(mt + 2) * 16 + kg * 4 + r] * acc[mt + 2][nt][r];
      }
    pA += __shfl_xor(pA, 16); pA += __shfl_xor(pA, 32);
    pB += __shfl_xor(pB, 16); pB += __shfl_xor(pB, 32);
    if (kg == 0) {
      float* dst = head ? hGi : hG;
      dst[(size_t)(blockIdx.x * 2)     * 64 + s] = pA + fbv * sg_lds[head][0];
      dst[(size_t)(blockIdx.x * 2 + 1) * 64 + s] = pB + fbv * sg_lds[head][1];
    }
  }
}

// ---------------------------------------------------------------------------
extern "C" void kernel_launch(void* const* d_in, const int* in_sizes, int n_in,
                              void* d_out, int out_size, void* d_ws, size_t ws_size,
                              hipStream_t stream)
{
  (void)in_sizes; (void)n_in; (void)out_size; (void)ws_size;

  const float* h    = (const float*)d_in[0];
  const float* msgW = (const float*)d_in[1];
  const float* msgb = (const float*)d_in[2];
  const float* Wih  = (const float*)d_in[3];
  const float* Whh  = (const float*)d_in[4];
  const float* bih  = (const float*)d_in[5];
  const float* bhh  = (const float*)d_in[6];
  const float* fmW  = (const float*)d_in[7];
  const float* fmb  = (const float*)d_in[8];
  const float* gmW  = (const float*)d_in[9];
  const float* gmb  = (const float*)d_in[10];
  const float* fmiW = (const float*)d_in[11];
  const float* fmib = (const float*)d_in[12];
  const float* gmiW = (const float*)d_in[13];
  const float* gmib = (const float*)d_in[14];
  const int*   ei   = (const int*)d_in[15];
  const int* e0 = ei;
  const int* e1 = ei + EDGES;

  // ---- workspace carve ----
  char* w = (char*)d_ws;
  const size_t NF = (size_t)NNODE * NDIM_;
  unsigned short* P1b  = (unsigned short*)w;  w += NF * 2;
  unsigned char*  P2b  = (unsigned char*)w;   w += NF;          // fp8
  unsigned short* aggb = (unsigned short*)w;  w += NF * 2;
  unsigned short* hb   = (unsigned short*)w;  w += NF * 2;
  unsigned short* hnb  = (unsigned short*)w;  w += NF * 2;
  int* cnt  = (int*)w;                        w += (size_t)NNODE * 4;
  int* offs = (int*)w;                        w += (size_t)(NNODE + 64) * 4;
  int* cur  = (int*)w;                        w += (size_t)NNODE * 4;
  int* adj  = (int*)w;                        w += (size_t)2 * EDGES * 4;
  int* bsum = (int*)w;                        w += 256 * 4;
  int* boff = (int*)w;                        w += 256 * 4;
  unsigned short* wm   = (unsigned short*)w;  w += (size_t)2 * 256 * 128 * 2;
  unsigned short* wrz  = (unsigned short*)w;  w += (size_t)2 * 256 * 256 * 2;
  unsigned short* wni  = (unsigned short*)w;  w += (size_t)2 * 128 * 128 * 2;
  unsigned short* wnh  = (unsigned short*)w;  w += (size_t)2 * 128 * 128 * 2;
  unsigned short* wcat = (unsigned short*)w;  w += (size_t)128 * 128 * 2;

  float* out_hn  = (float*)d_out;
  float* out_hG  = out_hn + NF;
  float* out_hGi = out_hG + (size_t)B_ * SDIM_;

  // ---- one-time: conversions (+cnt zero) + CSR ----
  convert_all_kernel<<<(int)(NF / 8 / 256), 256, 0, stream>>>(
      h, msgW, Wih, Whh, fmW, fmiW, hb, wm, wrz, wni, wnh, wcat, cnt);
  hist_kernel<<<EDGES / 256, 256, 0, stream>>>(e0, e1, cnt);
  scan1_kernel<<<NNODE / 256, 256, 0, stream>>>(cnt, offs, bsum);
  scan2_kernel<<<1, 256, 0, stream>>>(bsum, boff);
  scan3_kernel<<<NNODE / 256, 256, 0, stream>>>(cnt, offs, boff, cur);
  scatter_kernel<<<EDGES / 256, 256, 0, stream>>>(e0, e1, cur, adj);

  // ---- layer 0 ----
  proj_mfma_kernel<<<NNODE / 64, 256, 0, stream>>>(hb, wm, msgb, P1b, P2b);
  agg_kernel<<<NNODE / 4, 256, 0, stream>>>(P1b, P2b, offs, adj, aggb);
  gru_proj_kernel<<<NNODE / 64, 256, 0, stream>>>(
      aggb, hb, wrz, wni, wnh, bih, bhh,
      wm + (size_t)256 * 128, msgb + 128, hnb, P1b, P2b);

  // ---- layer 1 + readout ----
  agg_kernel<<<NNODE / 4, 256, 0, stream>>>(P1b, P2b, offs, adj, aggb);
  gru_gated_kernel<<<NNODE / 64, 256, 0, stream>>>(
      aggb, hnb,
      wrz + (size_t)256 * 256, wni + (size_t)128 * 128, wnh + (size_t)128 * 128,
      bih + 384, bhh + 384,
      wcat, fmb, gmW, gmb, fmib, gmiW, gmib,
      out_hn, out_hG, out_hGi);
}